// Round 13
// baseline (2438.753 us; speedup 1.0000x reference)
//
#include <hip/hip_runtime.h>

#define F 128
#define RB 64
#define RB_SHIFT 6
#define SCH 4096
#define PT3 512
#define EPT3 (SCH / PT3)
#define PTA 1024
#define NSEG 8
#define COL_BITS 17
#define COL_MASK 0x1FFFF
#define MAXNB 2048

// ---- fused: per-chunk histogram (low blockIdx) + weight fp32->int8 (rest) ----
__global__ __launch_bounds__(256) void cvt_chist_kernel(
    const float2* __restrict__ w2, ushort* __restrict__ wq, float* __restrict__ scales,
    int n_nodes, const int* __restrict__ rows, int* __restrict__ cntmat, int n_edges,
    int nb, int nchunks) {
    if ((int)blockIdx.x < nchunks) {
        __shared__ int h[MAXNB];
        int c = blockIdx.x, t = threadIdx.x;
        for (int i = t; i < nb; i += 256) h[i] = 0;
        __syncthreads();
        int e0 = c * SCH, e1 = min(e0 + SCH, n_edges);
        for (int e = e0 + t; e < e1; e += 256) atomicAdd(&h[rows[e] >> RB_SHIFT], 1);
        __syncthreads();
        for (int i = t; i < nb; i += 256) cntmat[(size_t)c * nb + i] = h[i];
    } else {
        int row = (blockIdx.x - nchunks) * 4 + (threadIdx.x >> 6);
        if (row >= n_nodes) return;
        int lane = threadIdx.x & 63;
        float2 f = w2[(size_t)row * 64 + lane];
        float m = fmaxf(fabsf(f.x), fabsf(f.y));
        for (int off = 32; off; off >>= 1) m = fmaxf(m, __shfl_xor(m, off));
        float inv = m > 0.f ? 127.f / m : 0.f;
        int q0 = (int)rintf(f.x * inv);
        int q1 = (int)rintf(f.y * inv);
        wq[(size_t)row * 64 + lane] = (ushort)((q0 & 0xFF) | ((q1 & 0xFF) << 8));
        if (lane == 0) scales[row] = m * (1.f / 127.f);
    }
}

// ---- P2a: per-segment exclusive scan along chunks (lane-per-bucket) ----
__global__ __launch_bounds__(256) void scanA_kernel(int* __restrict__ cntmat,
                                                    int* __restrict__ segsum,
                                                    int nb, int nchunks) {
    int b = blockIdx.x * 256 + threadIdx.x;
    if (b >= nb) return;
    int sg = blockIdx.y;
    int cps = (nchunks + NSEG - 1) / NSEG;
    int c0 = sg * cps, c1 = min(c0 + cps, nchunks);
    int run = 0;
#pragma unroll 4
    for (int c = c0; c < c1; c++) {
        int v = cntmat[(size_t)c * nb + b];
        cntmat[(size_t)c * nb + b] = run;
        run += v;
    }
    segsum[sg * nb + b] = run;
}

// ---- P2b merged: scan segment sums per bucket, then block-scan -> boffs ----
__global__ void scanBC_kernel(int* __restrict__ segsum, int* __restrict__ boffs, int nb) {
    __shared__ int lds[1024];
    int t = threadIdx.x;
    int per = (nb + 1023) / 1024;  // <= 2 since nb <= MAXNB
    int base = t * per;
    int cnt[2] = {0, 0};
    int s = 0;
    for (int i = 0; i < per && i < 2; i++) {
        int b = base + i;
        int run = 0;
        if (b < nb) {
            for (int sg = 0; sg < NSEG; sg++) {
                int v = segsum[sg * nb + b];
                segsum[sg * nb + b] = run;
                run += v;
            }
        }
        cnt[i] = run;
        s += run;
    }
    lds[t] = s;
    __syncthreads();
    for (int off = 1; off < 1024; off <<= 1) {
        int a = (t >= off) ? lds[t - off] : 0;
        __syncthreads();
        lds[t] += a;
        __syncthreads();
    }
    int excl = lds[t] - s;
    for (int i = 0; i < per && i < 2; i++) {
        int b = base + i;
        if (b < nb) {
            boffs[b] = excl;
            excl += cnt[i];
        }
    }
    if (t == 1023) boffs[nb] = lds[1023];
}

// ---- P3: exact-position scatter (wave-level scan), LDS-sorted contiguous writes ----
__global__ __launch_bounds__(PT3) void scatter_kernel(
    const int* __restrict__ rows, const int* __restrict__ cols,
    const float* __restrict__ vals, const float* __restrict__ scales,
    const int* __restrict__ boffs, const int* __restrict__ segsum,
    const int* __restrict__ cntmat, int2* __restrict__ epk, int n_edges, int nb,
    int nchunks) {
    __shared__ int relc[MAXNB];
    __shared__ int hist[MAXNB];
    __shared__ int lcur[MAXNB];
    __shared__ int2 buf[SCH];
    __shared__ int sidx[SCH];
    __shared__ int wsum[PT3 / 64], wbase[PT3 / 64];
    int t = threadIdx.x;
    int lane = t & 63, w = t >> 6;
    int cps = (nchunks + NSEG - 1) / NSEG;
    int c = blockIdx.x;

    int e0 = c * SCH, e1 = min(e0 + SCH, n_edges);
    int cnt = e1 - e0;
    int sg = c / cps;

    for (int i = t; i < nb; i += PT3) {
        relc[i] = boffs[i] + segsum[sg * nb + i] + cntmat[(size_t)c * nb + i];
        hist[i] = 0;
    }
    __syncthreads();

    int er[EPT3], ec[EPT3];
    float ev[EPT3];
#pragma unroll
    for (int k = 0; k < EPT3; k++) {
        int e = e0 + t + k * PT3;
        if (e < e1) {
            er[k] = rows[e];
            ec[k] = cols[e];
            ev[k] = vals[e] * scales[ec[k]];
            atomicAdd(&hist[er[k] >> RB_SHIFT], 1);
        }
    }
    __syncthreads();

    // block exclusive scan of hist[0..nb): wave-level
    int b0 = t << 2;  // MAXNB / PT3 == 4
    int h0 = (b0 + 0 < nb) ? hist[b0 + 0] : 0;
    int h1 = (b0 + 1 < nb) ? hist[b0 + 1] : 0;
    int h2 = (b0 + 2 < nb) ? hist[b0 + 2] : 0;
    int h3 = (b0 + 3 < nb) ? hist[b0 + 3] : 0;
    int psum = h0 + h1 + h2 + h3;
    int v = psum;
#pragma unroll
    for (int off = 1; off < 64; off <<= 1) {
        int a = __shfl_up(v, off);
        if (lane >= off) v += a;
    }
    if (lane == 63) wsum[w] = v;
    __syncthreads();
    if (t == 0) {
        int run = 0;
        for (int i = 0; i < PT3 / 64; i++) {
            wbase[i] = run;
            run += wsum[i];
        }
    }
    __syncthreads();
    int excl = v - psum + wbase[w];
    if (b0 + 0 < nb) { lcur[b0 + 0] = excl; relc[b0 + 0] -= excl; }
    excl += h0;
    if (b0 + 1 < nb) { lcur[b0 + 1] = excl; relc[b0 + 1] -= excl; }
    excl += h1;
    if (b0 + 2 < nb) { lcur[b0 + 2] = excl; relc[b0 + 2] -= excl; }
    excl += h2;
    if (b0 + 3 < nb) { lcur[b0 + 3] = excl; relc[b0 + 3] -= excl; }
    __syncthreads();

    // LDS sort: buf[p] = payload, sidx[p] = exact global position
#pragma unroll
    for (int k = 0; k < EPT3; k++) {
        int e = e0 + t + k * PT3;
        if (e < e1) {
            int b = er[k] >> RB_SHIFT;
            int p = atomicAdd(&lcur[b], 1);
            buf[p] = make_int2(ec[k] | ((er[k] & (RB - 1)) << COL_BITS),
                               __float_as_int(ev[k]));
            sidx[p] = relc[b] + p;
        }
    }
    __syncthreads();

    for (int i = t; i < cnt; i += PT3) epk[sidx[i]] = buf[i];
}

// ---- accum: unsorted LDS-atomic accumulate per bucket + bias + write ----
__global__ __launch_bounds__(PTA, 8) void accum_kernel(
    const int* __restrict__ boffs, const int2* __restrict__ epk,
    const ushort* __restrict__ wq, const float* __restrict__ bias,
    float* __restrict__ out, int n_nodes) {
    __shared__ int2 buf[SCH];        // 32 KB staging
    __shared__ float accx[RB * 64];  // 16 KB
    __shared__ float accy[RB * 64];  // 16 KB
    int b = blockIdx.x;
    int s = boffs[b];
    int cnt = boffs[b + 1] - s;
    int row0 = b << RB_SHIFT;
    int t = threadIdx.x;
    int lane = t & 63, w = t >> 6;

    for (int i = t; i < RB * 64; i += PTA) {
        accx[i] = 0.f;
        accy[i] = 0.f;
    }
    __syncthreads();

    const ushort* wql = wq + lane;
    float* axl = accx + lane;
    float* ayl = accy + lane;

#define DQX(u) ((float)(int)(signed char)((u) & 0xFF))
#define DQY(u) ((float)((int)(short)(u) >> 8))

    for (int base = 0; base < cnt; base += SCH) {
        int ntile = min(SCH, cnt - base);
        for (int i = t; i < ntile; i += PTA) buf[i] = epk[s + base + i];
        __syncthreads();

        int lo = (ntile * w) >> 4;
        int hi = (ntile * (w + 1)) >> 4;
        int e = lo;
        for (; e + 8 <= hi; e += 8) {
            int2 p0 = buf[e], p1 = buf[e + 1], p2 = buf[e + 2], p3 = buf[e + 3];
            int2 p4 = buf[e + 4], p5 = buf[e + 5], p6 = buf[e + 6], p7 = buf[e + 7];
            uint u0 = wql[((uint)p0.x & COL_MASK) << 6];
            uint u1 = wql[((uint)p1.x & COL_MASK) << 6];
            uint u2 = wql[((uint)p2.x & COL_MASK) << 6];
            uint u3 = wql[((uint)p3.x & COL_MASK) << 6];
            uint u4 = wql[((uint)p4.x & COL_MASK) << 6];
            uint u5 = wql[((uint)p5.x & COL_MASK) << 6];
            uint u6 = wql[((uint)p6.x & COL_MASK) << 6];
            uint u7 = wql[((uint)p7.x & COL_MASK) << 6];
            float v0 = __int_as_float(p0.y), v1 = __int_as_float(p1.y);
            float v2 = __int_as_float(p2.y), v3 = __int_as_float(p3.y);
            float v4 = __int_as_float(p4.y), v5 = __int_as_float(p5.y);
            float v6 = __int_as_float(p6.y), v7 = __int_as_float(p7.y);
            int r0 = ((uint)p0.x >> COL_BITS) << 6;
            int r1 = ((uint)p1.x >> COL_BITS) << 6;
            int r2 = ((uint)p2.x >> COL_BITS) << 6;
            int r3 = ((uint)p3.x >> COL_BITS) << 6;
            int r4 = ((uint)p4.x >> COL_BITS) << 6;
            int r5 = ((uint)p5.x >> COL_BITS) << 6;
            int r6 = ((uint)p6.x >> COL_BITS) << 6;
            int r7 = ((uint)p7.x >> COL_BITS) << 6;
            atomicAdd(axl + r0, v0 * DQX(u0));
            atomicAdd(ayl + r0, v0 * DQY(u0));
            atomicAdd(axl + r1, v1 * DQX(u1));
            atomicAdd(ayl + r1, v1 * DQY(u1));
            atomicAdd(axl + r2, v2 * DQX(u2));
            atomicAdd(ayl + r2, v2 * DQY(u2));
            atomicAdd(axl + r3, v3 * DQX(u3));
            atomicAdd(ayl + r3, v3 * DQY(u3));
            atomicAdd(axl + r4, v4 * DQX(u4));
            atomicAdd(ayl + r4, v4 * DQY(u4));
            atomicAdd(axl + r5, v5 * DQX(u5));
            atomicAdd(ayl + r5, v5 * DQY(u5));
            atomicAdd(axl + r6, v6 * DQX(u6));
            atomicAdd(ayl + r6, v6 * DQY(u6));
            atomicAdd(axl + r7, v7 * DQX(u7));
            atomicAdd(ayl + r7, v7 * DQY(u7));
        }
        for (; e < hi; ++e) {
            int2 pk = buf[e];
            uint u = wql[((uint)pk.x & COL_MASK) << 6];
            float v = __int_as_float(pk.y);
            int r = ((uint)pk.x >> COL_BITS) << 6;
            atomicAdd(axl + r, v * DQX(u));
            atomicAdd(ayl + r, v * DQY(u));
        }
        __syncthreads();
    }
#undef DQX
#undef DQY

    float2 bb = ((const float2*)bias)[lane];
#pragma unroll
    for (int j = 0; j < 4; j++) {
        int rl = w + j * 16;
        int gr = row0 + rl;
        if (gr < n_nodes) {
            ((float2*)(out + (size_t)gr * F))[lane] =
                make_float2(accx[(rl << 6) + lane] + bb.x,
                            accy[(rl << 6) + lane] + bb.y);
        }
    }
}

// ---------------- fallback: atomic path (fp32, exact) ----------------
__global__ void init_out_kernel(float* __restrict__ out, const float* __restrict__ bias,
                                int n_nodes) {
    const float4* b4 = (const float4*)bias;
    float4* o4 = (float4*)out;
    int total = n_nodes * (F / 4);
    for (int i = blockIdx.x * blockDim.x + threadIdx.x; i < total;
         i += gridDim.x * blockDim.x)
        o4[i] = b4[i & (F / 4 - 1)];
}

__global__ void edge_scatter_kernel(const int* __restrict__ rows,
                                    const int* __restrict__ cols,
                                    const float* __restrict__ vals,
                                    const float* __restrict__ weight,
                                    float* __restrict__ out, int n_edges) {
    int e = (blockIdx.x * blockDim.x + threadIdx.x) >> 6;
    if (e >= n_edges) return;
    int lane = threadIdx.x & 63;
    float2 w = ((const float2*)(weight + (size_t)cols[e] * F))[lane];
    float val = vals[e];
    float* o = out + (size_t)rows[e] * F + lane * 2;
    unsafeAtomicAdd(o, val * w.x);
    unsafeAtomicAdd(o + 1, val * w.y);
}

extern "C" void kernel_launch(void* const* d_in, const int* in_sizes, int n_in,
                              void* d_out, int out_size, void* d_ws, size_t ws_size,
                              hipStream_t stream) {
    const int*   rows   = (const int*)d_in[0];
    const int*   cols   = (const int*)d_in[1];
    const float* vals   = (const float*)d_in[2];
    const float* weight = (const float*)d_in[3];
    const float* bias   = (const float*)d_in[4];
    float* out = (float*)d_out;

    int n_edges = in_sizes[0];
    int n_nodes = out_size / F;
    int nb = (n_nodes + RB - 1) / RB;
    int nchunks = (n_edges + SCH - 1) / SCH;

    // ws: boffs[nb+1] | pad8 | epk[E] | scales[N] | pad | wq[N*64 u16]
    //     | pad | cntmat[nchunks*nb] | segsum[NSEG*nb]
    size_t head_ints  = ((size_t)nb + 2) & ~(size_t)1;
    size_t epk_off    = head_ints * 4;
    size_t scales_off = epk_off + (size_t)n_edges * 8;
    size_t wq_off     = (scales_off + (size_t)n_nodes * 4 + 255) & ~(size_t)255;
    size_t mat_off    = (wq_off + (size_t)n_nodes * F + 255) & ~(size_t)255;
    size_t seg_off    = mat_off + (size_t)nchunks * nb * 4;
    size_t need       = seg_off + (size_t)NSEG * nb * 4;

    if (ws_size < need || n_nodes > (1 << COL_BITS) || nb > MAXNB) {
        init_out_kernel<<<2048, 256, 0, stream>>>(out, bias, n_nodes);
        int grid = (n_edges + 3) / 4;
        edge_scatter_kernel<<<grid, 256, 0, stream>>>(rows, cols, vals, weight, out,
                                                      n_edges);
        return;
    }

    int* boffs    = (int*)d_ws;  // nb+1
    int2* epk     = (int2*)((char*)d_ws + epk_off);
    float* scales = (float*)((char*)d_ws + scales_off);
    ushort* wq    = (ushort*)((char*)d_ws + wq_off);
    int* cntmat   = (int*)((char*)d_ws + mat_off);
    int* segsum   = (int*)((char*)d_ws + seg_off);

    int cvt_blocks = (n_nodes + 3) / 4;
    cvt_chist_kernel<<<nchunks + cvt_blocks, 256, 0, stream>>>(
        (const float2*)weight, wq, scales, n_nodes, rows, cntmat, n_edges, nb, nchunks);
    dim3 ga((nb + 255) / 256, NSEG);
    scanA_kernel<<<ga, 256, 0, stream>>>(cntmat, segsum, nb, nchunks);
    scanBC_kernel<<<1, 1024, 0, stream>>>(segsum, boffs, nb);
    scatter_kernel<<<nchunks, PT3, 0, stream>>>(rows, cols, vals, scales, boffs, segsum,
                                                cntmat, epk, n_edges, nb, nchunks);
    accum_kernel<<<nb, PTA, 0, stream>>>(boffs, epk, wq, bias, out, n_nodes);
}

// Round 14
// 2432.361 us; speedup vs baseline: 1.0026x; 1.0026x over previous
//
#include <hip/hip_runtime.h>

#define F 128
#define RB 64
#define RB_SHIFT 6
#define SCH 4096
#define PT3 512
#define EPT3 (SCH / PT3)
#define PTA 1024
#define NSEG 8
#define COL_BITS 17
#define COL_MASK 0x1FFFF
#define MAXNB 2048

// ---- fused: per-chunk histogram (low blockIdx) + weight fp32->int8 (rest) ----
__global__ __launch_bounds__(256) void cvt_chist_kernel(
    const float2* __restrict__ w2, ushort* __restrict__ wq, float* __restrict__ scales,
    int n_nodes, const int* __restrict__ rows, int* __restrict__ cntmat, int n_edges,
    int nb, int nchunks) {
    if ((int)blockIdx.x < nchunks) {
        __shared__ int h[MAXNB];
        int c = blockIdx.x, t = threadIdx.x;
        for (int i = t; i < nb; i += 256) h[i] = 0;
        __syncthreads();
        int e0 = c * SCH, e1 = min(e0 + SCH, n_edges);
        for (int e = e0 + t; e < e1; e += 256) atomicAdd(&h[rows[e] >> RB_SHIFT], 1);
        __syncthreads();
        for (int i = t; i < nb; i += 256) cntmat[(size_t)c * nb + i] = h[i];
    } else {
        int row = (blockIdx.x - nchunks) * 4 + (threadIdx.x >> 6);
        if (row >= n_nodes) return;
        int lane = threadIdx.x & 63;
        float2 f = w2[(size_t)row * 64 + lane];
        float m = fmaxf(fabsf(f.x), fabsf(f.y));
        for (int off = 32; off; off >>= 1) m = fmaxf(m, __shfl_xor(m, off));
        float inv = m > 0.f ? 127.f / m : 0.f;
        int q0 = (int)rintf(f.x * inv);
        int q1 = (int)rintf(f.y * inv);
        wq[(size_t)row * 64 + lane] = (ushort)((q0 & 0xFF) | ((q1 & 0xFF) << 8));
        if (lane == 0) scales[row] = m * (1.f / 127.f);
    }
}

// ---- P2a: per-segment exclusive scan along chunks (lane-per-bucket) ----
__global__ __launch_bounds__(256) void scanA_kernel(int* __restrict__ cntmat,
                                                    int* __restrict__ segsum,
                                                    int nb, int nchunks) {
    int b = blockIdx.x * 256 + threadIdx.x;
    if (b >= nb) return;
    int sg = blockIdx.y;
    int cps = (nchunks + NSEG - 1) / NSEG;
    int c0 = sg * cps, c1 = min(c0 + cps, nchunks);
    int run = 0;
#pragma unroll 4
    for (int c = c0; c < c1; c++) {
        int v = cntmat[(size_t)c * nb + b];
        cntmat[(size_t)c * nb + b] = run;
        run += v;
    }
    segsum[sg * nb + b] = run;
}

// ---- P2b merged: scan segment sums per bucket, then block-scan -> boffs ----
__global__ void scanBC_kernel(int* __restrict__ segsum, int* __restrict__ boffs, int nb) {
    __shared__ int lds[1024];
    int t = threadIdx.x;
    int per = (nb + 1023) / 1024;  // <= 2 since nb <= MAXNB
    int base = t * per;
    int cnt[2] = {0, 0};
    int s = 0;
    for (int i = 0; i < per && i < 2; i++) {
        int b = base + i;
        int run = 0;
        if (b < nb) {
            for (int sg = 0; sg < NSEG; sg++) {
                int v = segsum[sg * nb + b];
                segsum[sg * nb + b] = run;
                run += v;
            }
        }
        cnt[i] = run;
        s += run;
    }
    lds[t] = s;
    __syncthreads();
    for (int off = 1; off < 1024; off <<= 1) {
        int a = (t >= off) ? lds[t - off] : 0;
        __syncthreads();
        lds[t] += a;
        __syncthreads();
    }
    int excl = lds[t] - s;
    for (int i = 0; i < per && i < 2; i++) {
        int b = base + i;
        if (b < nb) {
            boffs[b] = excl;
            excl += cnt[i];
        }
    }
    if (t == 1023) boffs[nb] = lds[1023];
}

// ---- P3: exact-position scatter (wave-level scan), LDS-sorted contiguous writes ----
__global__ __launch_bounds__(PT3) void scatter_kernel(
    const int* __restrict__ rows, const int* __restrict__ cols,
    const float* __restrict__ vals, const float* __restrict__ scales,
    const int* __restrict__ boffs, const int* __restrict__ segsum,
    const int* __restrict__ cntmat, int2* __restrict__ epk, int n_edges, int nb,
    int nchunks) {
    __shared__ int relc[MAXNB];
    __shared__ int hist[MAXNB];
    __shared__ int lcur[MAXNB];
    __shared__ int2 buf[SCH];
    __shared__ int sidx[SCH];
    __shared__ int wsum[PT3 / 64], wbase[PT3 / 64];
    int t = threadIdx.x;
    int lane = t & 63, w = t >> 6;
    int cps = (nchunks + NSEG - 1) / NSEG;
    int c = blockIdx.x;

    int e0 = c * SCH, e1 = min(e0 + SCH, n_edges);
    int cnt = e1 - e0;
    int sg = c / cps;

    for (int i = t; i < nb; i += PT3) {
        relc[i] = boffs[i] + segsum[sg * nb + i] + cntmat[(size_t)c * nb + i];
        hist[i] = 0;
    }
    __syncthreads();

    int er[EPT3], ec[EPT3];
    float ev[EPT3];
#pragma unroll
    for (int k = 0; k < EPT3; k++) {
        int e = e0 + t + k * PT3;
        if (e < e1) {
            er[k] = rows[e];
            ec[k] = cols[e];
            ev[k] = vals[e] * scales[ec[k]];
            atomicAdd(&hist[er[k] >> RB_SHIFT], 1);
        }
    }
    __syncthreads();

    // block exclusive scan of hist[0..nb): wave-level
    int b0 = t << 2;  // MAXNB / PT3 == 4
    int h0 = (b0 + 0 < nb) ? hist[b0 + 0] : 0;
    int h1 = (b0 + 1 < nb) ? hist[b0 + 1] : 0;
    int h2 = (b0 + 2 < nb) ? hist[b0 + 2] : 0;
    int h3 = (b0 + 3 < nb) ? hist[b0 + 3] : 0;
    int psum = h0 + h1 + h2 + h3;
    int v = psum;
#pragma unroll
    for (int off = 1; off < 64; off <<= 1) {
        int a = __shfl_up(v, off);
        if (lane >= off) v += a;
    }
    if (lane == 63) wsum[w] = v;
    __syncthreads();
    if (t == 0) {
        int run = 0;
        for (int i = 0; i < PT3 / 64; i++) {
            wbase[i] = run;
            run += wsum[i];
        }
    }
    __syncthreads();
    int excl = v - psum + wbase[w];
    if (b0 + 0 < nb) { lcur[b0 + 0] = excl; relc[b0 + 0] -= excl; }
    excl += h0;
    if (b0 + 1 < nb) { lcur[b0 + 1] = excl; relc[b0 + 1] -= excl; }
    excl += h1;
    if (b0 + 2 < nb) { lcur[b0 + 2] = excl; relc[b0 + 2] -= excl; }
    excl += h2;
    if (b0 + 3 < nb) { lcur[b0 + 3] = excl; relc[b0 + 3] -= excl; }
    __syncthreads();

    // LDS sort: buf[p] = payload, sidx[p] = exact global position
#pragma unroll
    for (int k = 0; k < EPT3; k++) {
        int e = e0 + t + k * PT3;
        if (e < e1) {
            int b = er[k] >> RB_SHIFT;
            int p = atomicAdd(&lcur[b], 1);
            buf[p] = make_int2(ec[k] | ((er[k] & (RB - 1)) << COL_BITS),
                               __float_as_int(ev[k]));
            sidx[p] = relc[b] + p;
        }
    }
    __syncthreads();

    for (int i = t; i < cnt; i += PT3) epk[sidx[i]] = buf[i];
}

// ---- accum: unsorted LDS accumulate via hardware ds_add_f32 + bias + write ----
__global__ __launch_bounds__(PTA, 8) void accum_kernel(
    const int* __restrict__ boffs, const int2* __restrict__ epk,
    const ushort* __restrict__ wq, const float* __restrict__ bias,
    float* __restrict__ out, int n_nodes) {
    __shared__ int2 buf[SCH];        // 32 KB staging
    __shared__ float accx[RB * 64];  // 16 KB
    __shared__ float accy[RB * 64];  // 16 KB
    int b = blockIdx.x;
    int s = boffs[b];
    int cnt = boffs[b + 1] - s;
    int row0 = b << RB_SHIFT;
    int t = threadIdx.x;
    int lane = t & 63, w = t >> 6;

    for (int i = t; i < RB * 64; i += PTA) {
        accx[i] = 0.f;
        accy[i] = 0.f;
    }
    __syncthreads();

    const ushort* wql = wq + lane;
    float* axl = accx + lane;
    float* ayl = accy + lane;

#define DQX(u) ((float)(int)(signed char)((u) & 0xFF))
#define DQY(u) ((float)((int)(short)(u) >> 8))

    for (int base = 0; base < cnt; base += SCH) {
        int ntile = min(SCH, cnt - base);
        for (int i = t; i < ntile; i += PTA) buf[i] = epk[s + base + i];
        __syncthreads();

        int lo = (ntile * w) >> 4;
        int hi = (ntile * (w + 1)) >> 4;
        int e = lo;
        for (; e + 8 <= hi; e += 8) {
            int2 p0 = buf[e], p1 = buf[e + 1], p2 = buf[e + 2], p3 = buf[e + 3];
            int2 p4 = buf[e + 4], p5 = buf[e + 5], p6 = buf[e + 6], p7 = buf[e + 7];
            uint u0 = wql[((uint)p0.x & COL_MASK) << 6];
            uint u1 = wql[((uint)p1.x & COL_MASK) << 6];
            uint u2 = wql[((uint)p2.x & COL_MASK) << 6];
            uint u3 = wql[((uint)p3.x & COL_MASK) << 6];
            uint u4 = wql[((uint)p4.x & COL_MASK) << 6];
            uint u5 = wql[((uint)p5.x & COL_MASK) << 6];
            uint u6 = wql[((uint)p6.x & COL_MASK) << 6];
            uint u7 = wql[((uint)p7.x & COL_MASK) << 6];
            float v0 = __int_as_float(p0.y), v1 = __int_as_float(p1.y);
            float v2 = __int_as_float(p2.y), v3 = __int_as_float(p3.y);
            float v4 = __int_as_float(p4.y), v5 = __int_as_float(p5.y);
            float v6 = __int_as_float(p6.y), v7 = __int_as_float(p7.y);
            int r0 = ((uint)p0.x >> COL_BITS) << 6;
            int r1 = ((uint)p1.x >> COL_BITS) << 6;
            int r2 = ((uint)p2.x >> COL_BITS) << 6;
            int r3 = ((uint)p3.x >> COL_BITS) << 6;
            int r4 = ((uint)p4.x >> COL_BITS) << 6;
            int r5 = ((uint)p5.x >> COL_BITS) << 6;
            int r6 = ((uint)p6.x >> COL_BITS) << 6;
            int r7 = ((uint)p7.x >> COL_BITS) << 6;
            unsafeAtomicAdd(axl + r0, v0 * DQX(u0));
            unsafeAtomicAdd(ayl + r0, v0 * DQY(u0));
            unsafeAtomicAdd(axl + r1, v1 * DQX(u1));
            unsafeAtomicAdd(ayl + r1, v1 * DQY(u1));
            unsafeAtomicAdd(axl + r2, v2 * DQX(u2));
            unsafeAtomicAdd(ayl + r2, v2 * DQY(u2));
            unsafeAtomicAdd(axl + r3, v3 * DQX(u3));
            unsafeAtomicAdd(ayl + r3, v3 * DQY(u3));
            unsafeAtomicAdd(axl + r4, v4 * DQX(u4));
            unsafeAtomicAdd(ayl + r4, v4 * DQY(u4));
            unsafeAtomicAdd(axl + r5, v5 * DQX(u5));
            unsafeAtomicAdd(ayl + r5, v5 * DQY(u5));
            unsafeAtomicAdd(axl + r6, v6 * DQX(u6));
            unsafeAtomicAdd(ayl + r6, v6 * DQY(u6));
            unsafeAtomicAdd(axl + r7, v7 * DQX(u7));
            unsafeAtomicAdd(ayl + r7, v7 * DQY(u7));
        }
        for (; e < hi; ++e) {
            int2 pk = buf[e];
            uint u = wql[((uint)pk.x & COL_MASK) << 6];
            float v = __int_as_float(pk.y);
            int r = ((uint)pk.x >> COL_BITS) << 6;
            unsafeAtomicAdd(axl + r, v * DQX(u));
            unsafeAtomicAdd(ayl + r, v * DQY(u));
        }
        __syncthreads();
    }
#undef DQX
#undef DQY

    float2 bb = ((const float2*)bias)[lane];
#pragma unroll
    for (int j = 0; j < 4; j++) {
        int rl = w + j * 16;
        int gr = row0 + rl;
        if (gr < n_nodes) {
            ((float2*)(out + (size_t)gr * F))[lane] =
                make_float2(accx[(rl << 6) + lane] + bb.x,
                            accy[(rl << 6) + lane] + bb.y);
        }
    }
}

// ---------------- fallback: atomic path (fp32, exact) ----------------
__global__ void init_out_kernel(float* __restrict__ out, const float* __restrict__ bias,
                                int n_nodes) {
    const float4* b4 = (const float4*)bias;
    float4* o4 = (float4*)out;
    int total = n_nodes * (F / 4);
    for (int i = blockIdx.x * blockDim.x + threadIdx.x; i < total;
         i += gridDim.x * blockDim.x)
        o4[i] = b4[i & (F / 4 - 1)];
}

__global__ void edge_scatter_kernel(const int* __restrict__ rows,
                                    const int* __restrict__ cols,
                                    const float* __restrict__ vals,
                                    const float* __restrict__ weight,
                                    float* __restrict__ out, int n_edges) {
    int e = (blockIdx.x * blockDim.x + threadIdx.x) >> 6;
    if (e >= n_edges) return;
    int lane = threadIdx.x & 63;
    float2 w = ((const float2*)(weight + (size_t)cols[e] * F))[lane];
    float val = vals[e];
    float* o = out + (size_t)rows[e] * F + lane * 2;
    unsafeAtomicAdd(o, val * w.x);
    unsafeAtomicAdd(o + 1, val * w.y);
}

extern "C" void kernel_launch(void* const* d_in, const int* in_sizes, int n_in,
                              void* d_out, int out_size, void* d_ws, size_t ws_size,
                              hipStream_t stream) {
    const int*   rows   = (const int*)d_in[0];
    const int*   cols   = (const int*)d_in[1];
    const float* vals   = (const float*)d_in[2];
    const float* weight = (const float*)d_in[3];
    const float* bias   = (const float*)d_in[4];
    float* out = (float*)d_out;

    int n_edges = in_sizes[0];
    int n_nodes = out_size / F;
    int nb = (n_nodes + RB - 1) / RB;
    int nchunks = (n_edges + SCH - 1) / SCH;

    // ws: boffs[nb+1] | pad8 | epk[E] | scales[N] | pad | wq[N*64 u16]
    //     | pad | cntmat[nchunks*nb] | segsum[NSEG*nb]
    size_t head_ints  = ((size_t)nb + 2) & ~(size_t)1;
    size_t epk_off    = head_ints * 4;
    size_t scales_off = epk_off + (size_t)n_edges * 8;
    size_t wq_off     = (scales_off + (size_t)n_nodes * 4 + 255) & ~(size_t)255;
    size_t mat_off    = (wq_off + (size_t)n_nodes * F + 255) & ~(size_t)255;
    size_t seg_off    = mat_off + (size_t)nchunks * nb * 4;
    size_t need       = seg_off + (size_t)NSEG * nb * 4;

    if (ws_size < need || n_nodes > (1 << COL_BITS) || nb > MAXNB) {
        init_out_kernel<<<2048, 256, 0, stream>>>(out, bias, n_nodes);
        int grid = (n_edges + 3) / 4;
        edge_scatter_kernel<<<grid, 256, 0, stream>>>(rows, cols, vals, weight, out,
                                                      n_edges);
        return;
    }

    int* boffs    = (int*)d_ws;  // nb+1
    int2* epk     = (int2*)((char*)d_ws + epk_off);
    float* scales = (float*)((char*)d_ws + scales_off);
    ushort* wq    = (ushort*)((char*)d_ws + wq_off);
    int* cntmat   = (int*)((char*)d_ws + mat_off);
    int* segsum   = (int*)((char*)d_ws + seg_off);

    int cvt_blocks = (n_nodes + 3) / 4;
    cvt_chist_kernel<<<nchunks + cvt_blocks, 256, 0, stream>>>(
        (const float2*)weight, wq, scales, n_nodes, rows, cntmat, n_edges, nb, nchunks);
    dim3 ga((nb + 255) / 256, NSEG);
    scanA_kernel<<<ga, 256, 0, stream>>>(cntmat, segsum, nb, nchunks);
    scanBC_kernel<<<1, 1024, 0, stream>>>(segsum, boffs, nb);
    scatter_kernel<<<nchunks, PT3, 0, stream>>>(rows, cols, vals, scales, boffs, segsum,
                                                cntmat, epk, n_edges, nb, nchunks);
    accum_kernel<<<nb, PTA, 0, stream>>>(boffs, epk, wq, bias, out, n_nodes);
}

// Round 15
// 149.478 us; speedup vs baseline: 16.3151x; 16.2724x over previous
//
#include <hip/hip_runtime.h>

#define F 128
#define RB 64
#define RB_SHIFT 6
#define CAP 4096
#define SCH 4096
#define PT3 512
#define EPT3 (SCH / PT3)
#define NSEG 8
#define COL_BITS 17
#define COL_MASK 0x1FFFF
#define MAXNB 2048

// ---- fused: per-chunk histogram (low blockIdx) + weight fp32->int8 (rest) ----
__global__ __launch_bounds__(256) void cvt_chist_kernel(
    const float2* __restrict__ w2, ushort* __restrict__ wq, float* __restrict__ scales,
    int n_nodes, const int* __restrict__ rows, int* __restrict__ cntmat, int n_edges,
    int nb, int nchunks) {
    if ((int)blockIdx.x < nchunks) {
        __shared__ int h[MAXNB];
        int c = blockIdx.x, t = threadIdx.x;
        for (int i = t; i < nb; i += 256) h[i] = 0;
        __syncthreads();
        int e0 = c * SCH, e1 = min(e0 + SCH, n_edges);
        for (int e = e0 + t; e < e1; e += 256) atomicAdd(&h[rows[e] >> RB_SHIFT], 1);
        __syncthreads();
        for (int i = t; i < nb; i += 256) cntmat[(size_t)c * nb + i] = h[i];
    } else {
        int row = (blockIdx.x - nchunks) * 4 + (threadIdx.x >> 6);
        if (row >= n_nodes) return;
        int lane = threadIdx.x & 63;
        float2 f = w2[(size_t)row * 64 + lane];
        float m = fmaxf(fabsf(f.x), fabsf(f.y));
        for (int off = 32; off; off >>= 1) m = fmaxf(m, __shfl_xor(m, off));
        float inv = m > 0.f ? 127.f / m : 0.f;
        int q0 = (int)rintf(f.x * inv);
        int q1 = (int)rintf(f.y * inv);
        wq[(size_t)row * 64 + lane] = (ushort)((q0 & 0xFF) | ((q1 & 0xFF) << 8));
        if (lane == 0) scales[row] = m * (1.f / 127.f);
    }
}

// ---- P2a: per-segment exclusive scan along chunks (lane-per-bucket) ----
__global__ __launch_bounds__(256) void scanA_kernel(int* __restrict__ cntmat,
                                                    int* __restrict__ segsum,
                                                    int nb, int nchunks) {
    int b = blockIdx.x * 256 + threadIdx.x;
    if (b >= nb) return;
    int sg = blockIdx.y;
    int cps = (nchunks + NSEG - 1) / NSEG;
    int c0 = sg * cps, c1 = min(c0 + cps, nchunks);
    int run = 0;
#pragma unroll 4
    for (int c = c0; c < c1; c++) {
        int v = cntmat[(size_t)c * nb + b];
        cntmat[(size_t)c * nb + b] = run;
        run += v;
    }
    segsum[sg * nb + b] = run;
}

// ---- P2b merged: scan segment sums per bucket, then block-scan -> boffs ----
__global__ void scanBC_kernel(int* __restrict__ segsum, int* __restrict__ boffs, int nb) {
    __shared__ int lds[1024];
    int t = threadIdx.x;
    int per = (nb + 1023) / 1024;  // <= 2 since nb <= MAXNB
    int base = t * per;
    int cnt[2] = {0, 0};
    int s = 0;
    for (int i = 0; i < per && i < 2; i++) {
        int b = base + i;
        int run = 0;
        if (b < nb) {
            for (int sg = 0; sg < NSEG; sg++) {
                int v = segsum[sg * nb + b];
                segsum[sg * nb + b] = run;
                run += v;
            }
        }
        cnt[i] = run;
        s += run;
    }
    lds[t] = s;
    __syncthreads();
    for (int off = 1; off < 1024; off <<= 1) {
        int a = (t >= off) ? lds[t - off] : 0;
        __syncthreads();
        lds[t] += a;
        __syncthreads();
    }
    int excl = lds[t] - s;
    for (int i = 0; i < per && i < 2; i++) {
        int b = base + i;
        if (b < nb) {
            boffs[b] = excl;
            excl += cnt[i];
        }
    }
    if (t == 1023) boffs[nb] = lds[1023];
}

// ---- P3: exact-position scatter (wave-level scan), LDS-sorted contiguous writes ----
__global__ __launch_bounds__(PT3) void scatter_kernel(
    const int* __restrict__ rows, const int* __restrict__ cols,
    const float* __restrict__ vals, const float* __restrict__ scales,
    const int* __restrict__ boffs, const int* __restrict__ segsum,
    const int* __restrict__ cntmat, int2* __restrict__ epk, int n_edges, int nb,
    int nchunks) {
    __shared__ int relc[MAXNB];
    __shared__ int hist[MAXNB];
    __shared__ int lcur[MAXNB];
    __shared__ int2 buf[SCH];
    __shared__ int sidx[SCH];
    __shared__ int wsum[PT3 / 64], wbase[PT3 / 64];
    int t = threadIdx.x;
    int lane = t & 63, w = t >> 6;
    int cps = (nchunks + NSEG - 1) / NSEG;
    int c = blockIdx.x;

    int e0 = c * SCH, e1 = min(e0 + SCH, n_edges);
    int cnt = e1 - e0;
    int sg = c / cps;

    for (int i = t; i < nb; i += PT3) {
        relc[i] = boffs[i] + segsum[sg * nb + i] + cntmat[(size_t)c * nb + i];
        hist[i] = 0;
    }
    __syncthreads();

    int er[EPT3], ec[EPT3];
    float ev[EPT3];
#pragma unroll
    for (int k = 0; k < EPT3; k++) {
        int e = e0 + t + k * PT3;
        if (e < e1) {
            er[k] = rows[e];
            ec[k] = cols[e];
            ev[k] = vals[e] * scales[ec[k]];
            atomicAdd(&hist[er[k] >> RB_SHIFT], 1);
        }
    }
    __syncthreads();

    // block exclusive scan of hist[0..nb): wave-level
    int b0 = t << 2;  // MAXNB / PT3 == 4
    int h0 = (b0 + 0 < nb) ? hist[b0 + 0] : 0;
    int h1 = (b0 + 1 < nb) ? hist[b0 + 1] : 0;
    int h2 = (b0 + 2 < nb) ? hist[b0 + 2] : 0;
    int h3 = (b0 + 3 < nb) ? hist[b0 + 3] : 0;
    int psum = h0 + h1 + h2 + h3;
    int v = psum;
#pragma unroll
    for (int off = 1; off < 64; off <<= 1) {
        int a = __shfl_up(v, off);
        if (lane >= off) v += a;
    }
    if (lane == 63) wsum[w] = v;
    __syncthreads();
    if (t == 0) {
        int run = 0;
        for (int i = 0; i < PT3 / 64; i++) {
            wbase[i] = run;
            run += wsum[i];
        }
    }
    __syncthreads();
    int excl = v - psum + wbase[w];
    if (b0 + 0 < nb) { lcur[b0 + 0] = excl; relc[b0 + 0] -= excl; }
    excl += h0;
    if (b0 + 1 < nb) { lcur[b0 + 1] = excl; relc[b0 + 1] -= excl; }
    excl += h1;
    if (b0 + 2 < nb) { lcur[b0 + 2] = excl; relc[b0 + 2] -= excl; }
    excl += h2;
    if (b0 + 3 < nb) { lcur[b0 + 3] = excl; relc[b0 + 3] -= excl; }
    __syncthreads();

    // LDS sort: buf[p] = payload, sidx[p] = exact global position
#pragma unroll
    for (int k = 0; k < EPT3; k++) {
        int e = e0 + t + k * PT3;
        if (e < e1) {
            int b = er[k] >> RB_SHIFT;
            int p = atomicAdd(&lcur[b], 1);
            buf[p] = make_int2(ec[k] | ((er[k] & (RB - 1)) << COL_BITS),
                               __float_as_int(ev[k]));
            sidx[p] = relc[b] + p;
        }
    }
    __syncthreads();

    for (int i = t; i < cnt; i += PT3) epk[sidx[i]] = buf[i];
}

// ---- fused: LDS row-sort of bucket + int8 gather accumulate + bias + write ----
__global__ __launch_bounds__(512, 8) void sortacc_kernel(
    const int* __restrict__ boffs, const int2* __restrict__ epk,
    const ushort* __restrict__ wq, const float* __restrict__ bias,
    float* __restrict__ out, int n_nodes) {
    __shared__ int2 buf[CAP];  // 32 KB
    __shared__ int hist[RB], lstart[RB], lcur[RB];
    int b = blockIdx.x;
    int s = boffs[b];
    int cnt = boffs[b + 1] - s;
    int row0 = b << RB_SHIFT;
    int t = threadIdx.x;
    int lane = t & 63, w = t >> 6;
    float2 bb = ((const float2*)bias)[lane];

#define DEQX(u) ((float)(int)(signed char)((u) & 0xFF))
#define DEQY(u) ((float)((int)(short)(u) >> 8))
#define WOFF(px) ((((uint)(px) & COL_MASK) << 6) | (uint)lane)

    if (cnt <= CAP) {
        if (t < RB) hist[t] = 0;
        __syncthreads();
        int2 r0, r1, r2, r3, r4, r5, r6, r7;
#define LOADK(rk, k)                                                     \
        {                                                                \
            int i = t + (k)*512;                                         \
            if (i < cnt) {                                               \
                rk = epk[s + i];                                         \
                atomicAdd(&hist[(unsigned)rk.x >> COL_BITS], 1);         \
            }                                                            \
        }
        LOADK(r0, 0) LOADK(r1, 1) LOADK(r2, 2) LOADK(r3, 3)
        LOADK(r4, 4) LOADK(r5, 5) LOADK(r6, 6) LOADK(r7, 7)
#undef LOADK
        __syncthreads();
        if (w == 0) {  // wave-level exclusive scan of 64 hist entries
            int hv = hist[lane];
            int v = hv;
#pragma unroll
            for (int off = 1; off < 64; off <<= 1) {
                int a = __shfl_up(v, off);
                if (lane >= off) v += a;
            }
            lstart[lane] = v - hv;
            lcur[lane] = v - hv;
        }
        __syncthreads();
        // scatter: row bits are dead after this point -> store pre-shifted
        // column element-offset, gather addr becomes single v_add
#define SCATK(rk, k)                                                         \
        {                                                                    \
            int i = t + (k)*512;                                             \
            if (i < cnt) {                                                   \
                int p = atomicAdd(&lcur[(unsigned)rk.x >> COL_BITS], 1);     \
                buf[p] = make_int2((int)(((uint)rk.x & COL_MASK) << 6), rk.y);\
            }                                                                \
        }
        SCATK(r0, 0) SCATK(r1, 1) SCATK(r2, 2) SCATK(r3, 3)
        SCATK(r4, 4) SCATK(r5, 5) SCATK(r6, 6) SCATK(r7, 7)
#undef SCATK
        __syncthreads();

        // wave w accumulates rows w*8 .. w*8+7; 12-deep gather pipeline
        for (int j = 0; j < 8; j++) {
            int rl = w * 8 + j;
            int gr = row0 + rl;
            if (gr >= n_nodes) break;
            int e = lstart[rl];
            int end = e + hist[rl];
            float ax = 0.f, ay = 0.f;
            for (; e + 12 <= end; e += 12) {
                int2 p0 = buf[e],     p1 = buf[e + 1], p2 = buf[e + 2];
                int2 p3 = buf[e + 3], p4 = buf[e + 4], p5 = buf[e + 5];
                int2 p6 = buf[e + 6], p7 = buf[e + 7], p8 = buf[e + 8];
                int2 p9 = buf[e + 9], pa = buf[e + 10], pb = buf[e + 11];
                uint u0 = wq[(uint)p0.x + lane];
                uint u1 = wq[(uint)p1.x + lane];
                uint u2 = wq[(uint)p2.x + lane];
                uint u3 = wq[(uint)p3.x + lane];
                uint u4 = wq[(uint)p4.x + lane];
                uint u5 = wq[(uint)p5.x + lane];
                uint u6 = wq[(uint)p6.x + lane];
                uint u7 = wq[(uint)p7.x + lane];
                uint u8 = wq[(uint)p8.x + lane];
                uint u9 = wq[(uint)p9.x + lane];
                uint ua = wq[(uint)pa.x + lane];
                uint ub = wq[(uint)pb.x + lane];
                float v0 = __int_as_float(p0.y), v1 = __int_as_float(p1.y);
                float v2 = __int_as_float(p2.y), v3 = __int_as_float(p3.y);
                float v4 = __int_as_float(p4.y), v5 = __int_as_float(p5.y);
                float v6 = __int_as_float(p6.y), v7 = __int_as_float(p7.y);
                float v8 = __int_as_float(p8.y), v9 = __int_as_float(p9.y);
                float va = __int_as_float(pa.y), vb = __int_as_float(pb.y);
                ax += v0 * DEQX(u0) + v1 * DEQX(u1) + v2 * DEQX(u2) + v3 * DEQX(u3) +
                      v4 * DEQX(u4) + v5 * DEQX(u5) + v6 * DEQX(u6) + v7 * DEQX(u7) +
                      v8 * DEQX(u8) + v9 * DEQX(u9) + va * DEQX(ua) + vb * DEQX(ub);
                ay += v0 * DEQY(u0) + v1 * DEQY(u1) + v2 * DEQY(u2) + v3 * DEQY(u3) +
                      v4 * DEQY(u4) + v5 * DEQY(u5) + v6 * DEQY(u6) + v7 * DEQY(u7) +
                      v8 * DEQY(u8) + v9 * DEQY(u9) + va * DEQY(ua) + vb * DEQY(ub);
            }
            for (; e + 4 <= end; e += 4) {
                int2 p0 = buf[e], p1 = buf[e + 1], p2 = buf[e + 2], p3 = buf[e + 3];
                uint u0 = wq[(uint)p0.x + lane];
                uint u1 = wq[(uint)p1.x + lane];
                uint u2 = wq[(uint)p2.x + lane];
                uint u3 = wq[(uint)p3.x + lane];
                float v0 = __int_as_float(p0.y), v1 = __int_as_float(p1.y);
                float v2 = __int_as_float(p2.y), v3 = __int_as_float(p3.y);
                ax += v0 * DEQX(u0) + v1 * DEQX(u1) + v2 * DEQX(u2) + v3 * DEQX(u3);
                ay += v0 * DEQY(u0) + v1 * DEQY(u1) + v2 * DEQY(u2) + v3 * DEQY(u3);
            }
            for (; e < end; ++e) {
                int2 pk = buf[e];
                uint u = wq[(uint)pk.x + lane];
                float v = __int_as_float(pk.y);
                ax += v * DEQX(u);
                ay += v * DEQY(u);
            }
            ((float2*)(out + (size_t)gr * F))[lane] = make_float2(ax + bb.x, ay + bb.y);
        }
    } else {
        // overflow bucket: filter scan from global (correct, ~never taken)
        for (int j = 0; j < 8; j++) {
            int rl = w * 8 + j;
            int gr = row0 + rl;
            if (gr >= n_nodes) break;
            float ax = 0.f, ay = 0.f;
            for (int e = s; e < s + cnt; ++e) {
                int2 pk = epk[e];
                if ((int)((unsigned)pk.x >> COL_BITS) == rl) {
                    uint u = wq[WOFF(pk.x)];
                    float v = __int_as_float(pk.y);
                    ax += v * DEQX(u);
                    ay += v * DEQY(u);
                }
            }
            ((float2*)(out + (size_t)gr * F))[lane] = make_float2(ax + bb.x, ay + bb.y);
        }
    }
#undef DEQX
#undef DEQY
#undef WOFF
}

// ---------------- fallback: atomic path (fp32, exact) ----------------
__global__ void init_out_kernel(float* __restrict__ out, const float* __restrict__ bias,
                                int n_nodes) {
    const float4* b4 = (const float4*)bias;
    float4* o4 = (float4*)out;
    int total = n_nodes * (F / 4);
    for (int i = blockIdx.x * blockDim.x + threadIdx.x; i < total;
         i += gridDim.x * blockDim.x)
        o4[i] = b4[i & (F / 4 - 1)];
}

__global__ void edge_scatter_kernel(const int* __restrict__ rows,
                                    const int* __restrict__ cols,
                                    const float* __restrict__ vals,
                                    const float* __restrict__ weight,
                                    float* __restrict__ out, int n_edges) {
    int e = (blockIdx.x * blockDim.x + threadIdx.x) >> 6;
    if (e >= n_edges) return;
    int lane = threadIdx.x & 63;
    float2 w = ((const float2*)(weight + (size_t)cols[e] * F))[lane];
    float val = vals[e];
    float* o = out + (size_t)rows[e] * F + lane * 2;
    unsafeAtomicAdd(o, val * w.x);
    unsafeAtomicAdd(o + 1, val * w.y);
}

extern "C" void kernel_launch(void* const* d_in, const int* in_sizes, int n_in,
                              void* d_out, int out_size, void* d_ws, size_t ws_size,
                              hipStream_t stream) {
    const int*   rows   = (const int*)d_in[0];
    const int*   cols   = (const int*)d_in[1];
    const float* vals   = (const float*)d_in[2];
    const float* weight = (const float*)d_in[3];
    const float* bias   = (const float*)d_in[4];
    float* out = (float*)d_out;

    int n_edges = in_sizes[0];
    int n_nodes = out_size / F;
    int nb = (n_nodes + RB - 1) / RB;
    int nchunks = (n_edges + SCH - 1) / SCH;

    // ws: boffs[nb+1] | pad8 | epk[E] | scales[N] | pad | wq[N*64 u16]
    //     | pad | cntmat[nchunks*nb] | segsum[NSEG*nb]
    size_t head_ints  = ((size_t)nb + 2) & ~(size_t)1;
    size_t epk_off    = head_ints * 4;
    size_t scales_off = epk_off + (size_t)n_edges * 8;
    size_t wq_off     = (scales_off + (size_t)n_nodes * 4 + 255) & ~(size_t)255;
    size_t mat_off    = (wq_off + (size_t)n_nodes * F + 255) & ~(size_t)255;
    size_t seg_off    = mat_off + (size_t)nchunks * nb * 4;
    size_t need       = seg_off + (size_t)NSEG * nb * 4;

    if (ws_size < need || n_nodes > (1 << COL_BITS) || nb > MAXNB) {
        init_out_kernel<<<2048, 256, 0, stream>>>(out, bias, n_nodes);
        int grid = (n_edges + 3) / 4;
        edge_scatter_kernel<<<grid, 256, 0, stream>>>(rows, cols, vals, weight, out,
                                                      n_edges);
        return;
    }

    int* boffs    = (int*)d_ws;  // nb+1
    int2* epk     = (int2*)((char*)d_ws + epk_off);
    float* scales = (float*)((char*)d_ws + scales_off);
    ushort* wq    = (ushort*)((char*)d_ws + wq_off);
    int* cntmat   = (int*)((char*)d_ws + mat_off);
    int* segsum   = (int*)((char*)d_ws + seg_off);

    int cvt_blocks = (n_nodes + 3) / 4;
    cvt_chist_kernel<<<nchunks + cvt_blocks, 256, 0, stream>>>(
        (const float2*)weight, wq, scales, n_nodes, rows, cntmat, n_edges, nb, nchunks);
    dim3 ga((nb + 255) / 256, NSEG);
    scanA_kernel<<<ga, 256, 0, stream>>>(cntmat, segsum, nb, nchunks);
    scanBC_kernel<<<1, 1024, 0, stream>>>(segsum, boffs, nb);
    scatter_kernel<<<nchunks, PT3, 0, stream>>>(rows, cols, vals, scales, boffs, segsum,
                                                cntmat, epk, n_edges, nb, nchunks);
    sortacc_kernel<<<nb, 512, 0, stream>>>(boffs, epk, wq, bias, out, n_nodes);
}

// Round 16
// 145.659 us; speedup vs baseline: 16.7429x; 1.0262x over previous
//
#include <hip/hip_runtime.h>

#define F 128
#define RB 64
#define RB_SHIFT 6
#define CAP 4096
#define SCH 4096
#define PT3 1024
#define EPT3 (SCH / PT3)   // 4 edges per thread in scatter
#define NSEG 8
#define COL_BITS 17
#define COL_MASK 0x1FFFF
#define MAXNB 2048

// ---- fused: per-chunk histogram (low blockIdx) + weight fp32->int8 (rest) ----
__global__ __launch_bounds__(256) void cvt_chist_kernel(
    const float4* __restrict__ w4, uint* __restrict__ wq32, float* __restrict__ scales,
    int total4, const int* __restrict__ rows, int* __restrict__ cntmat, int n_edges,
    int nb, int nchunks) {
    if ((int)blockIdx.x < nchunks) {
        __shared__ int h[MAXNB];
        int c = blockIdx.x, t = threadIdx.x;
        for (int i = t; i < nb; i += 256) h[i] = 0;
        __syncthreads();
        int e0 = c * SCH, e1 = min(e0 + SCH, n_edges);
        if (e1 - e0 == SCH) {
            const int4* r4 = (const int4*)(rows + e0);
#pragma unroll
            for (int k = 0; k < 4; k++) {
                int4 rv = r4[k * 256 + t];
                atomicAdd(&h[rv.x >> RB_SHIFT], 1);
                atomicAdd(&h[rv.y >> RB_SHIFT], 1);
                atomicAdd(&h[rv.z >> RB_SHIFT], 1);
                atomicAdd(&h[rv.w >> RB_SHIFT], 1);
            }
        } else {
            for (int e = e0 + t; e < e1; e += 256) atomicAdd(&h[rows[e] >> RB_SHIFT], 1);
        }
        __syncthreads();
        for (int i = t; i < nb; i += 256) cntmat[(size_t)c * nb + i] = h[i];
    } else {
        int idx = (blockIdx.x - nchunks) * 256 + threadIdx.x;
        if (idx >= total4) return;
        float4 f = w4[idx];
        float m = fmaxf(fmaxf(fabsf(f.x), fabsf(f.y)), fmaxf(fabsf(f.z), fabsf(f.w)));
#pragma unroll
        for (int off = 1; off <= 16; off <<= 1) m = fmaxf(m, __shfl_xor(m, off));
        // m = row max over the 32-thread group (32 float4 = one 128-feature row)
        float inv = m > 0.f ? 127.f / m : 0.f;
        int q0 = (int)rintf(f.x * inv);
        int q1 = (int)rintf(f.y * inv);
        int q2 = (int)rintf(f.z * inv);
        int q3 = (int)rintf(f.w * inv);
        wq32[idx] = (q0 & 0xFF) | ((q1 & 0xFF) << 8) | ((q2 & 0xFF) << 16) |
                    ((q3 & 0xFF) << 24);
        if ((idx & 31) == 0) scales[idx >> 5] = m * (1.f / 127.f);
    }
}

// ---- P2a: per-segment exclusive scan along chunks (lane-per-bucket) ----
__global__ __launch_bounds__(256) void scanA_kernel(int* __restrict__ cntmat,
                                                    int* __restrict__ segsum,
                                                    int nb, int nchunks) {
    int b = blockIdx.x * 256 + threadIdx.x;
    if (b >= nb) return;
    int sg = blockIdx.y;
    int cps = (nchunks + NSEG - 1) / NSEG;
    int c0 = sg * cps, c1 = min(c0 + cps, nchunks);
    int run = 0;
#pragma unroll 4
    for (int c = c0; c < c1; c++) {
        int v = cntmat[(size_t)c * nb + b];
        cntmat[(size_t)c * nb + b] = run;
        run += v;
    }
    segsum[sg * nb + b] = run;
}

// ---- P2b merged: scan segment sums per bucket, then block-scan -> boffs ----
__global__ void scanBC_kernel(int* __restrict__ segsum, int* __restrict__ boffs, int nb) {
    __shared__ int lds[1024];
    int t = threadIdx.x;
    int per = (nb + 1023) / 1024;  // <= 2 since nb <= MAXNB
    int base = t * per;
    int cnt[2] = {0, 0};
    int s = 0;
    for (int i = 0; i < per && i < 2; i++) {
        int b = base + i;
        int run = 0;
        if (b < nb) {
            for (int sg = 0; sg < NSEG; sg++) {
                int v = segsum[sg * nb + b];
                segsum[sg * nb + b] = run;
                run += v;
            }
        }
        cnt[i] = run;
        s += run;
    }
    lds[t] = s;
    __syncthreads();
    for (int off = 1; off < 1024; off <<= 1) {
        int a = (t >= off) ? lds[t - off] : 0;
        __syncthreads();
        lds[t] += a;
        __syncthreads();
    }
    int excl = lds[t] - s;
    for (int i = 0; i < per && i < 2; i++) {
        int b = base + i;
        if (b < nb) {
            boffs[b] = excl;
            excl += cnt[i];
        }
    }
    if (t == 1023) boffs[nb] = lds[1023];
}

// ---- P3: exact-position scatter (wave-level scan), LDS-sorted contiguous writes ----
__global__ __launch_bounds__(PT3) void scatter_kernel(
    const int* __restrict__ rows, const int* __restrict__ cols,
    const float* __restrict__ vals, const float* __restrict__ scales,
    const int* __restrict__ boffs, const int* __restrict__ segsum,
    const int* __restrict__ cntmat, int2* __restrict__ epk, int n_edges, int nb,
    int nchunks) {
    __shared__ int relc[MAXNB];
    __shared__ int hist[MAXNB];
    __shared__ int lcur[MAXNB];
    __shared__ int2 buf[SCH];
    __shared__ ushort sbkt[SCH];
    __shared__ int wsum[PT3 / 64], wbase[PT3 / 64];
    int t = threadIdx.x;
    int lane = t & 63, w = t >> 6;
    int cps = (nchunks + NSEG - 1) / NSEG;
    int c = blockIdx.x;

    int e0 = c * SCH, e1 = min(e0 + SCH, n_edges);
    int cnt = e1 - e0;
    int sg = c / cps;

    for (int i = t; i < nb; i += PT3) {
        relc[i] = boffs[i] + segsum[sg * nb + i] + cntmat[(size_t)c * nb + i];
        hist[i] = 0;
    }
    __syncthreads();

    int er[EPT3], ec[EPT3];
    float ev[EPT3];
    int eb = e0 + (t << 2);
    if (eb + 4 <= e1) {
        int4 rv = *(const int4*)(rows + eb);
        int4 cv = *(const int4*)(cols + eb);
        float4 vv = *(const float4*)(vals + eb);
        er[0] = rv.x; er[1] = rv.y; er[2] = rv.z; er[3] = rv.w;
        ec[0] = cv.x; ec[1] = cv.y; ec[2] = cv.z; ec[3] = cv.w;
        ev[0] = vv.x * scales[ec[0]];
        ev[1] = vv.y * scales[ec[1]];
        ev[2] = vv.z * scales[ec[2]];
        ev[3] = vv.w * scales[ec[3]];
#pragma unroll
        for (int k = 0; k < 4; k++) atomicAdd(&hist[er[k] >> RB_SHIFT], 1);
    } else {
#pragma unroll
        for (int k = 0; k < 4; k++) {
            int e = eb + k;
            if (e < e1) {
                er[k] = rows[e];
                ec[k] = cols[e];
                ev[k] = vals[e] * scales[ec[k]];
                atomicAdd(&hist[er[k] >> RB_SHIFT], 1);
            }
        }
    }
    __syncthreads();

    // block exclusive scan of hist[0..nb): wave-level (2 buckets per thread)
    int b0 = t << 1;  // MAXNB / PT3 == 2
    int h0 = (b0 + 0 < nb) ? hist[b0 + 0] : 0;
    int h1 = (b0 + 1 < nb) ? hist[b0 + 1] : 0;
    int psum = h0 + h1;
    int v = psum;
#pragma unroll
    for (int off = 1; off < 64; off <<= 1) {
        int a = __shfl_up(v, off);
        if (lane >= off) v += a;
    }
    if (lane == 63) wsum[w] = v;
    __syncthreads();
    if (t == 0) {
        int run = 0;
        for (int i = 0; i < PT3 / 64; i++) {
            wbase[i] = run;
            run += wsum[i];
        }
    }
    __syncthreads();
    int excl = v - psum + wbase[w];
    if (b0 + 0 < nb) { lcur[b0 + 0] = excl; relc[b0 + 0] -= excl; }
    excl += h0;
    if (b0 + 1 < nb) { lcur[b0 + 1] = excl; relc[b0 + 1] -= excl; }
    __syncthreads();

    // LDS sort: buf[p] = payload, sbkt[p] = bucket id
#pragma unroll
    for (int k = 0; k < EPT3; k++) {
        int e = eb + k;
        if (e < e1) {
            int b = er[k] >> RB_SHIFT;
            int p = atomicAdd(&lcur[b], 1);
            buf[p] = make_int2(ec[k] | ((er[k] & (RB - 1)) << COL_BITS),
                               __float_as_int(ev[k]));
            sbkt[p] = (ushort)b;
        }
    }
    __syncthreads();

    for (int i = t; i < cnt; i += PT3) epk[relc[sbkt[i]] + i] = buf[i];
}

// ---- fused: LDS row-sort of bucket + int8 gather accumulate + bias + write ----
__global__ __launch_bounds__(512, 8) void sortacc_kernel(
    const int* __restrict__ boffs, const int2* __restrict__ epk,
    const ushort* __restrict__ wq, const float* __restrict__ bias,
    float* __restrict__ out, int n_nodes) {
    __shared__ int2 buf[CAP];  // 32 KB
    __shared__ int hist[RB], lstart[RB], lcur[RB];
    int b = blockIdx.x;
    int s = boffs[b];
    int cnt = boffs[b + 1] - s;
    int row0 = b << RB_SHIFT;
    int t = threadIdx.x;
    int lane = t & 63, w = t >> 6;
    float2 bb = ((const float2*)bias)[lane];

#define DEQX(u) ((float)(int)(signed char)((u) & 0xFF))
#define DEQY(u) ((float)((int)(short)(u) >> 8))
#define WOFF(px) ((((uint)(px) & COL_MASK) << 6) | (uint)lane)

    if (cnt <= CAP) {
        if (t < RB) hist[t] = 0;
        __syncthreads();
        int2 r0, r1, r2, r3, r4, r5, r6, r7;
#define LOADK(rk, k)                                                     \
        {                                                                \
            int i = t + (k)*512;                                         \
            if (i < cnt) {                                               \
                rk = epk[s + i];                                         \
                atomicAdd(&hist[(unsigned)rk.x >> COL_BITS], 1);         \
            }                                                            \
        }
        LOADK(r0, 0) LOADK(r1, 1) LOADK(r2, 2) LOADK(r3, 3)
        LOADK(r4, 4) LOADK(r5, 5) LOADK(r6, 6) LOADK(r7, 7)
#undef LOADK
        __syncthreads();
        if (w == 0) {  // wave-level exclusive scan of 64 hist entries
            int hv = hist[lane];
            int v = hv;
#pragma unroll
            for (int off = 1; off < 64; off <<= 1) {
                int a = __shfl_up(v, off);
                if (lane >= off) v += a;
            }
            lstart[lane] = v - hv;
            lcur[lane] = v - hv;
        }
        __syncthreads();
        // scatter: row bits dead after this -> store pre-shifted column offset
#define SCATK(rk, k)                                                         \
        {                                                                    \
            int i = t + (k)*512;                                             \
            if (i < cnt) {                                                   \
                int p = atomicAdd(&lcur[(unsigned)rk.x >> COL_BITS], 1);     \
                buf[p] = make_int2((int)(((uint)rk.x & COL_MASK) << 6), rk.y);\
            }                                                                \
        }
        SCATK(r0, 0) SCATK(r1, 1) SCATK(r2, 2) SCATK(r3, 3)
        SCATK(r4, 4) SCATK(r5, 5) SCATK(r6, 6) SCATK(r7, 7)
#undef SCATK
        __syncthreads();

        // wave w accumulates rows w*8 .. w*8+7; 12-deep gather pipeline
        for (int j = 0; j < 8; j++) {
            int rl = w * 8 + j;
            int gr = row0 + rl;
            if (gr >= n_nodes) break;
            int e = lstart[rl];
            int end = e + hist[rl];
            float ax = 0.f, ay = 0.f;
            for (; e + 12 <= end; e += 12) {
                int2 p0 = buf[e],     p1 = buf[e + 1], p2 = buf[e + 2];
                int2 p3 = buf[e + 3], p4 = buf[e + 4], p5 = buf[e + 5];
                int2 p6 = buf[e + 6], p7 = buf[e + 7], p8 = buf[e + 8];
                int2 p9 = buf[e + 9], pa = buf[e + 10], pb = buf[e + 11];
                uint u0 = wq[(uint)p0.x + lane];
                uint u1 = wq[(uint)p1.x + lane];
                uint u2 = wq[(uint)p2.x + lane];
                uint u3 = wq[(uint)p3.x + lane];
                uint u4 = wq[(uint)p4.x + lane];
                uint u5 = wq[(uint)p5.x + lane];
                uint u6 = wq[(uint)p6.x + lane];
                uint u7 = wq[(uint)p7.x + lane];
                uint u8 = wq[(uint)p8.x + lane];
                uint u9 = wq[(uint)p9.x + lane];
                uint ua = wq[(uint)pa.x + lane];
                uint ub = wq[(uint)pb.x + lane];
                float v0 = __int_as_float(p0.y), v1 = __int_as_float(p1.y);
                float v2 = __int_as_float(p2.y), v3 = __int_as_float(p3.y);
                float v4 = __int_as_float(p4.y), v5 = __int_as_float(p5.y);
                float v6 = __int_as_float(p6.y), v7 = __int_as_float(p7.y);
                float v8 = __int_as_float(p8.y), v9 = __int_as_float(p9.y);
                float va = __int_as_float(pa.y), vb = __int_as_float(pb.y);
                ax += v0 * DEQX(u0) + v1 * DEQX(u1) + v2 * DEQX(u2) + v3 * DEQX(u3) +
                      v4 * DEQX(u4) + v5 * DEQX(u5) + v6 * DEQX(u6) + v7 * DEQX(u7) +
                      v8 * DEQX(u8) + v9 * DEQX(u9) + va * DEQX(ua) + vb * DEQX(ub);
                ay += v0 * DEQY(u0) + v1 * DEQY(u1) + v2 * DEQY(u2) + v3 * DEQY(u3) +
                      v4 * DEQY(u4) + v5 * DEQY(u5) + v6 * DEQY(u6) + v7 * DEQY(u7) +
                      v8 * DEQY(u8) + v9 * DEQY(u9) + va * DEQY(ua) + vb * DEQY(ub);
            }
            for (; e + 4 <= end; e += 4) {
                int2 p0 = buf[e], p1 = buf[e + 1], p2 = buf[e + 2], p3 = buf[e + 3];
                uint u0 = wq[(uint)p0.x + lane];
                uint u1 = wq[(uint)p1.x + lane];
                uint u2 = wq[(uint)p2.x + lane];
                uint u3 = wq[(uint)p3.x + lane];
                float v0 = __int_as_float(p0.y), v1 = __int_as_float(p1.y);
                float v2 = __int_as_float(p2.y), v3 = __int_as_float(p3.y);
                ax += v0 * DEQX(u0) + v1 * DEQX(u1) + v2 * DEQX(u2) + v3 * DEQX(u3);
                ay += v0 * DEQY(u0) + v1 * DEQY(u1) + v2 * DEQY(u2) + v3 * DEQY(u3);
            }
            for (; e < end; ++e) {
                int2 pk = buf[e];
                uint u = wq[(uint)pk.x + lane];
                float v = __int_as_float(pk.y);
                ax += v * DEQX(u);
                ay += v * DEQY(u);
            }
            ((float2*)(out + (size_t)gr * F))[lane] = make_float2(ax + bb.x, ay + bb.y);
        }
    } else {
        // overflow bucket: filter scan from global (correct, ~never taken)
        for (int j = 0; j < 8; j++) {
            int rl = w * 8 + j;
            int gr = row0 + rl;
            if (gr >= n_nodes) break;
            float ax = 0.f, ay = 0.f;
            for (int e = s; e < s + cnt; ++e) {
                int2 pk = epk[e];
                if ((int)((unsigned)pk.x >> COL_BITS) == rl) {
                    uint u = wq[WOFF(pk.x)];
                    float v = __int_as_float(pk.y);
                    ax += v * DEQX(u);
                    ay += v * DEQY(u);
                }
            }
            ((float2*)(out + (size_t)gr * F))[lane] = make_float2(ax + bb.x, ay + bb.y);
        }
    }
#undef DEQX
#undef DEQY
#undef WOFF
}

// ---------------- fallback: atomic path (fp32, exact) ----------------
__global__ void init_out_kernel(float* __restrict__ out, const float* __restrict__ bias,
                                int n_nodes) {
    const float4* b4 = (const float4*)bias;
    float4* o4 = (float4*)out;
    int total = n_nodes * (F / 4);
    for (int i = blockIdx.x * blockDim.x + threadIdx.x; i < total;
         i += gridDim.x * blockDim.x)
        o4[i] = b4[i & (F / 4 - 1)];
}

__global__ void edge_scatter_kernel(const int* __restrict__ rows,
                                    const int* __restrict__ cols,
                                    const float* __restrict__ vals,
                                    const float* __restrict__ weight,
                                    float* __restrict__ out, int n_edges) {
    int e = (blockIdx.x * blockDim.x + threadIdx.x) >> 6;
    if (e >= n_edges) return;
    int lane = threadIdx.x & 63;
    float2 w = ((const float2*)(weight + (size_t)cols[e] * F))[lane];
    float val = vals[e];
    float* o = out + (size_t)rows[e] * F + lane * 2;
    unsafeAtomicAdd(o, val * w.x);
    unsafeAtomicAdd(o + 1, val * w.y);
}

extern "C" void kernel_launch(void* const* d_in, const int* in_sizes, int n_in,
                              void* d_out, int out_size, void* d_ws, size_t ws_size,
                              hipStream_t stream) {
    const int*   rows   = (const int*)d_in[0];
    const int*   cols   = (const int*)d_in[1];
    const float* vals   = (const float*)d_in[2];
    const float* weight = (const float*)d_in[3];
    const float* bias   = (const float*)d_in[4];
    float* out = (float*)d_out;

    int n_edges = in_sizes[0];
    int n_nodes = out_size / F;
    int nb = (n_nodes + RB - 1) / RB;
    int nchunks = (n_edges + SCH - 1) / SCH;

    // ws: boffs[nb+1] | pad8 | epk[E] | scales[N] | pad | wq[N*64 u16]
    //     | pad | cntmat[nchunks*nb] | segsum[NSEG*nb]
    size_t head_ints  = ((size_t)nb + 2) & ~(size_t)1;
    size_t epk_off    = head_ints * 4;
    size_t scales_off = epk_off + (size_t)n_edges * 8;
    size_t wq_off     = (scales_off + (size_t)n_nodes * 4 + 255) & ~(size_t)255;
    size_t mat_off    = (wq_off + (size_t)n_nodes * F + 255) & ~(size_t)255;
    size_t seg_off    = mat_off + (size_t)nchunks * nb * 4;
    size_t need       = seg_off + (size_t)NSEG * nb * 4;

    if (ws_size < need || n_nodes > (1 << COL_BITS) || nb > MAXNB) {
        init_out_kernel<<<2048, 256, 0, stream>>>(out, bias, n_nodes);
        int grid = (n_edges + 3) / 4;
        edge_scatter_kernel<<<grid, 256, 0, stream>>>(rows, cols, vals, weight, out,
                                                      n_edges);
        return;
    }

    int* boffs    = (int*)d_ws;  // nb+1
    int2* epk     = (int2*)((char*)d_ws + epk_off);
    float* scales = (float*)((char*)d_ws + scales_off);
    ushort* wq    = (ushort*)((char*)d_ws + wq_off);
    int* cntmat   = (int*)((char*)d_ws + mat_off);
    int* segsum   = (int*)((char*)d_ws + seg_off);

    int total4 = n_nodes * (F / 4);
    int cvt_blocks = (total4 + 255) / 256;
    cvt_chist_kernel<<<nchunks + cvt_blocks, 256, 0, stream>>>(
        (const float4*)weight, (uint*)wq, scales, total4, rows, cntmat, n_edges, nb,
        nchunks);
    dim3 ga((nb + 255) / 256, NSEG);
    scanA_kernel<<<ga, 256, 0, stream>>>(cntmat, segsum, nb, nchunks);
    scanBC_kernel<<<1, 1024, 0, stream>>>(segsum, boffs, nb);
    scatter_kernel<<<nchunks, PT3, 0, stream>>>(rows, cols, vals, scales, boffs, segsum,
                                                cntmat, epk, n_edges, nb, nchunks);
    sortacc_kernel<<<nb, 512, 0, stream>>>(boffs, epk, wq, bias, out, n_nodes);
}